// Round 6
// baseline (282.741 us; speedup 1.0000x reference)
//
#include <hip/hip_runtime.h>
#include <stdint.h>

typedef _Float16 f16;
typedef f16 half2_t __attribute__((ext_vector_type(2)));
typedef f16 half4_t __attribute__((ext_vector_type(4)));
typedef f16 half8_t __attribute__((ext_vector_type(8)));
typedef __fp16 fp16x2_t __attribute__((ext_vector_type(2)));
typedef float f32x4 __attribute__((ext_vector_type(4)));

#define N_ 4
#define S_ 2048
#define D_ 1024
#define H_ 16
#define HD_ 64
#define LOG2E 1.44269504088896340736f
#define SCALE_ 0.03125f   /* 1/sqrt(1024) */

typedef __attribute__((address_space(1))) void gvoid;
typedef __attribute__((address_space(3))) void lvoid;

__device__ __forceinline__ void load_lds16(const void* g, void* l) {
  __builtin_amdgcn_global_load_lds((gvoid*)(uintptr_t)g, (lvoid*)l, 16, 0, 0);
}

__device__ __forceinline__ f32x4 mfma32(half8_t a, half8_t b, f32x4 c) {
  return __builtin_amdgcn_mfma_f32_16x16x32_f16(a, b, c, 0, 0, 0);
}

__device__ __forceinline__ half2_t pack_f16(float a, float b) {
  fp16x2_t t = __builtin_amdgcn_cvt_pkrtz(a, b);
  return __builtin_bit_cast(half2_t, t);
}

// ---------------- weight prep (Wbig + Mq) ----------------
__global__ void wprep(const float* __restrict__ Wv, const float* __restrict__ Wo,
                      const float* __restrict__ Wq, const float* __restrict__ Wk,
                      f16* __restrict__ Wbig, float* __restrict__ Mq) {
  int b = blockIdx.x;
  if (b < 1024) {
    int j = b;
#pragma unroll
    for (int c = 0; c < 4; ++c) {
      int i = c * 256 + threadIdx.x;
      int h = i >> 6, dd = i & 63;
      const float* wo = Wo + (size_t)j * 1024 + h * 64;
      float acc = 0.f;
#pragma unroll 8
      for (int e = 0; e < 64; ++e) acc += Wv[e * 64 + dd] * wo[e];
      Wbig[(size_t)j * 1024 + i] = (f16)acc;
    }
  } else {
    int tid = (b - 1024) * 256 + threadIdx.x;  // 4096 threads
    int d = tid >> 6, e = tid & 63;
    float acc = 0.f;
#pragma unroll 8
    for (int r = 0; r < 64; ++r) acc += Wq[r * 64 + d] * Wk[r * 64 + e];
    Mq[d * 64 + e] = acc * (SCALE_ * LOG2E);
  }
}

// ---------------- prep2: Q-proj + K cast (blocks 0..511), V transpose (512..4607)
__global__ __launch_bounds__(256) void prep2(const float* __restrict__ Q,
                                             const float* __restrict__ K,
                                             const float* __restrict__ V,
                                             const float* __restrict__ Mq,
                                             f16* __restrict__ q16, f16* __restrict__ k16,
                                             f16* __restrict__ v16) {
  __shared__ char smem[16384];
  int b = blockIdx.x;
  if (b < 512) {
    float* mql = (float*)smem;
#pragma unroll
    for (int c = 0; c < 16; ++c) mql[c * 256 + threadIdx.x] = Mq[c * 256 + threadIdx.x];
    __syncthreads();
    int n = b >> 7, sblk = b & 127;
    int L = threadIdx.x & 63, w = threadIdx.x >> 6;
    int lq = L & 15, hh = w * 4 + (L >> 4);
    int s = sblk * 16 + lq;
    const float* qrow = Q + ((size_t)(n * S_ + s)) * D_ + hh * HD_;
    f32x4 acc4[16];
#pragma unroll
    for (int i = 0; i < 16; ++i) acc4[i] = (f32x4){0.f, 0.f, 0.f, 0.f};
    for (int d4 = 0; d4 < 16; ++d4) {
      f32x4 qv = *(const f32x4*)(qrow + d4 * 4);
#pragma unroll
      for (int dj = 0; dj < 4; ++dj) {
        const f32x4* mrow = (const f32x4*)(mql + (d4 * 4 + dj) * 64);  // broadcast reads
        float qs = qv[dj];
#pragma unroll
        for (int i = 0; i < 16; ++i) acc4[i] += mrow[i] * qs;
      }
    }
    size_t cbase = ((size_t)((n * 16 + hh) * 128 + sblk)) * 2;
#pragma unroll
    for (int dp = 0; dp < 2; ++dp) {
#pragma unroll
      for (int qd = 0; qd < 4; ++qd) {
        half8_t hv;
        f32x4 a0 = acc4[dp * 8 + qd * 2], a1 = acc4[dp * 8 + qd * 2 + 1];
#pragma unroll
        for (int j = 0; j < 4; ++j) { hv[j] = (f16)a0[j]; hv[4 + j] = (f16)a1[j]; }
        *(half8_t*)(q16 + (cbase + dp) * 512 + (qd * 16 + lq) * 8) = hv;
      }
    }
    const float* krow = K + ((size_t)(n * S_ + s)) * D_ + hh * HD_;
    f32x4 kr[16];
#pragma unroll
    for (int i = 0; i < 16; ++i) kr[i] = *(const f32x4*)(krow + i * 4);
#pragma unroll
    for (int dp = 0; dp < 2; ++dp) {
#pragma unroll
      for (int qd = 0; qd < 4; ++qd) {
        half8_t hv;
        f32x4 a0 = kr[dp * 8 + qd * 2], a1 = kr[dp * 8 + qd * 2 + 1];
#pragma unroll
        for (int j = 0; j < 4; ++j) { hv[j] = (f16)a0[j]; hv[4 + j] = (f16)a1[j]; }
        *(half8_t*)(k16 + (cbase + dp) * 512 + (qd * 16 + lq) * 8) = hv;
      }
    }
  } else {
    f16* lv = (f16*)smem;
    int b2 = b - 512;  // 4096 = 4 n * 16 h * 64 sb32
    int n = b2 >> 10, hh = (b2 >> 6) & 15, sb = b2 & 63;
    int t = threadIdx.x;
    {
      int r = t >> 3, ic = t & 7;
      const float* src = V + ((size_t)(n * S_ + sb * 32 + r)) * D_ + hh * HD_ + ic * 8;
      f32x4 a = *(const f32x4*)src;
      f32x4 b3 = *(const f32x4*)(src + 4);
      half8_t hv;
#pragma unroll
      for (int j = 0; j < 4; ++j) { hv[j] = (f16)a[j]; hv[4 + j] = (f16)b3[j]; }
      *(half8_t*)(lv + r * 64 + ic * 8) = hv;
    }
    __syncthreads();
    {
      int mt = t >> 6, L = t & 63;
      int quad = L >> 4, ld = L & 15;
      half8_t o;
#pragma unroll
      for (int j = 0; j < 4; ++j) {
        o[j]     = lv[(quad * 4 + j) * 64 + mt * 16 + ld];
        o[4 + j] = lv[(quad * 4 + j + 16) * 64 + mt * 16 + ld];
      }
      *(half8_t*)(v16 + (((size_t)(n * 16 + hh) * 64 + sb) * 4 + mt) * 512 + L * 8) = o;
    }
  }
}

// ---------------- flash v5.1: same as v5, split into two half-grid dispatches ------
// DIAGNOSTIC ROUND: the top-5 profile window has only ever shown flash (every flash
// dispatch >= every other kernel). Splitting flash over qt halves (qt0=0 / qt0=4)
// drops per-dispatch dur to ~single-block latency (~40 us), lowering the top-5
// visibility threshold so prep2/ogemm/wprep (the ~198 us invisible residue) can
// surface with counters. v5 is intra-wave pipelined, so 1 block/CU should cost
// little (rounds 1/3/4: TLP-independent).
__global__ __launch_bounds__(256, 2) void flash(const f16* __restrict__ q16,
                                                const f16* __restrict__ k16,
                                                const f16* __restrict__ v16,
                                                f16* __restrict__ att, int qt0) {
  int nh = blockIdx.x;          // 64 (n,h)
  int qt = blockIdx.y + qt0;    // 8 q-tiles of 256, split across two dispatches
  int L = threadIdx.x & 63, w = threadIdx.x >> 6;
  int lq = L & 15, quad = L >> 4;

  // q'' B-fragments for 4 slices of 16 q-rows each
  const half8_t* qg = (const half8_t*)q16;
  half8_t qB[4][2];
#pragma unroll
  for (int j = 0; j < 4; ++j) {
    size_t qc = ((size_t)(nh * 128 + qt * 16 + w * 4 + j)) * 2;
    qB[j][0] = qg[qc * 64 + L];
    qB[j][1] = qg[(qc + 1) * 64 + L];
  }

  f32x4 accO[4][4];
#pragma unroll
  for (int j = 0; j < 4; ++j)
#pragma unroll
    for (int i = 0; i < 4; ++i) accO[j][i] = (f32x4){0.f, 0.f, 0.f, 0.f};
  f32x4 lvec[4];
#pragma unroll
  for (int j = 0; j < 4; ++j) lvec[j] = (f32x4){0.f, 0.f, 0.f, 0.f};

  const char* kg = (const char*)k16 + (size_t)nh * 262144 + L * 16;
  const char* vg = (const char*)v16 + (size_t)nh * 262144 + L * 16;

  half8_t kfA[4], vfA[4], pb[4];
  f32x4 aQK[2][4];

#define QK16(KF)                                              \
  {                                                           \
    __builtin_amdgcn_s_setprio(1);                            \
    _Pragma("unroll")                                         \
    for (int u = 0; u < 2; ++u) {                             \
      _Pragma("unroll")                                       \
      for (int j = 0; j < 4; ++j) {                           \
        f32x4 a = (f32x4){0.f, 0.f, 0.f, 0.f};                \
        a = mfma32(KF[u * 2], qB[j][0], a);                   \
        a = mfma32(KF[u * 2 + 1], qB[j][1], a);               \
        aQK[u][j] = a;                                        \
      }                                                       \
    }                                                         \
    __builtin_amdgcn_s_setprio(0);                            \
  }

#define PV16(VF)                                              \
  {                                                           \
    __builtin_amdgcn_s_setprio(1);                            \
    _Pragma("unroll")                                         \
    for (int mt2 = 0; mt2 < 4; ++mt2) {                       \
      _Pragma("unroll")                                       \
      for (int j = 0; j < 4; ++j)                             \
        accO[j][mt2] = mfma32(VF[mt2], pb[j], accO[j][mt2]);  \
    }                                                         \
    __builtin_amdgcn_s_setprio(0);                            \
  }

#define EXPPACK                                                             \
  {                                                                         \
    half4_t pc[2][4];                                                       \
    _Pragma("unroll")                                                       \
    for (int u = 0; u < 2; ++u) {                                           \
      _Pragma("unroll")                                                     \
      for (int j = 0; j < 4; ++j) {                                         \
        f32x4 p;                                                            \
        _Pragma("unroll")                                                   \
        for (int r = 0; r < 4; ++r) p[r] = __builtin_amdgcn_exp2f(aQK[u][j][r]); \
        lvec[j] += p;                                                       \
        pc[u][j] = __builtin_shufflevector(pack_f16(p[0], p[1]),            \
                                           pack_f16(p[2], p[3]), 0, 1, 2, 3); \
      }                                                                     \
    }                                                                       \
    _Pragma("unroll")                                                       \
    for (int j = 0; j < 4; ++j)                                             \
      pb[j] = __builtin_shufflevector(pc[0][j], pc[1][j], 0, 1, 2, 3, 4, 5, 6, 7); \
  }

  // prologue: load k(0), v(0); QK(0); load k(1); exp/pack -> pb(0)
#pragma unroll
  for (int c = 0; c < 4; ++c) {
    kfA[c] = *(const half8_t*)(kg + c * 1024);
    vfA[c] = *(const half8_t*)(vg + c * 1024);
  }
  QK16(kfA);
#pragma unroll
  for (int c = 0; c < 4; ++c) kfA[c] = *(const half8_t*)(kg + 4096 + c * 1024);
  EXPPACK;

  for (int gg = 1; gg < 64; ++gg) {
    QK16(kfA);  // k(gg), loaded last iteration
    PV16(vfA);  // v(gg-1), loaded last iteration
    // refill: k(gg+1) and v(gg) — issued after their readers, land under exp+next QK
    if (gg + 1 < 64) {
      const char* kb = kg + (size_t)(gg + 1) * 4096;
#pragma unroll
      for (int c = 0; c < 4; ++c) kfA[c] = *(const half8_t*)(kb + c * 1024);
    }
    {
      const char* vb = vg + (size_t)gg * 4096;
#pragma unroll
      for (int c = 0; c < 4; ++c) vfA[c] = *(const half8_t*)(vb + c * 1024);
    }
    EXPPACK;  // pb(gg) — VALU, overlaps the 32-mfma cluster's pipe occupancy
  }
  PV16(vfA);  // v(63)

#undef QK16
#undef PV16
#undef EXPPACK

  int n = nh >> 4, h = nh & 15;
#pragma unroll
  for (int j = 0; j < 4; ++j) {
    float l = lvec[j][0] + lvec[j][1] + lvec[j][2] + lvec[j][3];
    l += __shfl_xor(l, 16, 64);
    l += __shfl_xor(l, 32, 64);
    float inv_l = 1.0f / l;
    int s = qt * 256 + w * 64 + j * 16 + lq;
    f16* orow = att + ((size_t)(n * S_ + s)) * D_ + h * HD_;
#pragma unroll
    for (int mt2 = 0; mt2 < 4; ++mt2) {
      half4_t o;
#pragma unroll
      for (int r = 0; r < 4; ++r) o[r] = (f16)(accO[j][mt2][r] * inv_l);
      *(half4_t*)(orow + mt2 * 16 + quad * 4) = o;
    }
  }
}

// ---------------- output GEMM: XOR-swizzled LDS, double-buffer, 1 barrier/iter ----
// (256,3): 3 blocks/CU (96KB LDS, VGPR cap 170 — no spill risk) for more TLP to
// cover the per-iter vmcnt-drain stall of the 2-phase structure.
__global__ __launch_bounds__(256, 3) void ogemm(const f16* __restrict__ A, const f16* __restrict__ Bm,
                                                const float* __restrict__ bias, float* __restrict__ C) {
  __shared__ char lds[32768];  // buf[2] x (A 8K + B 8K)
  int bm = blockIdx.x, bn = blockIdx.y;
  int L = threadIdx.x & 63, w = threadIdx.x >> 6;
  int wm = w >> 1, wn = w & 1;
  int lq = L & 15, quad = L >> 4;
  int lr = L >> 2, lc = L & 3;
  int src_c = lc ^ (lr & 3);  // stage global chunk src_c into LDS slot lc
  f32x4 acc[16];
#pragma unroll
  for (int i = 0; i < 16; ++i) acc[i] = (f32x4){0.f, 0.f, 0.f, 0.f};

  const f16* ga0 = A + ((size_t)(bm * 128 + (w * 2) * 16 + lr)) * 1024 + src_c * 8;
  const f16* gb0 = Bm + ((size_t)(bn * 128 + (w * 2) * 16 + lr)) * 1024 + src_c * 8;

  // prologue: stage kt 0 and 1
#pragma unroll
  for (int t = 0; t < 2; ++t)
#pragma unroll
    for (int c = 0; c < 2; ++c) {
      load_lds16(ga0 + t * 32 + (size_t)c * 16 * 1024, lds + t * 16384 + (w * 2 + c) * 1024);
      load_lds16(gb0 + t * 32 + (size_t)c * 16 * 1024, lds + t * 16384 + 8192 + (w * 2 + c) * 1024);
    }
  __syncthreads();

  for (int kt = 0; kt < 32; ++kt) {
    const char* base = lds + (kt & 1) * 16384;
    half8_t af[4], bf[4];
#pragma unroll
    for (int t = 0; t < 4; ++t) {
      int ch = quad ^ (lq & 3);
      af[t] = *(const half8_t*)(base + (wm * 64 + t * 16 + lq) * 64 + ch * 16);
      bf[t] = *(const half8_t*)(base + 8192 + (wn * 64 + t * 16 + lq) * 64 + ch * 16);
    }
#pragma unroll
    for (int mt = 0; mt < 4; ++mt)
#pragma unroll
      for (int nt = 0; nt < 4; ++nt)
        acc[mt * 4 + nt] =
            __builtin_amdgcn_mfma_f32_16x16x32_f16(af[mt], bf[nt], acc[mt * 4 + nt], 0, 0, 0);
    __syncthreads();  // frag reads done; drains kt+1 loads (overlapped w/ MFMA)
    if (kt + 2 < 32) {
      char* dst = lds + (kt & 1) * 16384;
#pragma unroll
      for (int c = 0; c < 2; ++c) {
        load_lds16(ga0 + (kt + 2) * 32 + (size_t)c * 16 * 1024, dst + (w * 2 + c) * 1024);
        load_lds16(gb0 + (kt + 2) * 32 + (size_t)c * 16 * 1024, dst + 8192 + (w * 2 + c) * 1024);
      }
    }
  }

#pragma unroll
  for (int nt = 0; nt < 4; ++nt) {
    int col = bn * 128 + wn * 64 + nt * 16 + lq;
    float bv = bias[col];
#pragma unroll
    for (int mt = 0; mt < 4; ++mt) {
#pragma unroll
      for (int r = 0; r < 4; ++r) {
        int row = bm * 128 + wm * 64 + mt * 16 + quad * 4 + r;
        C[(size_t)row * 1024 + col] = acc[mt * 4 + nt][r] + bv;
      }
    }
  }
}

extern "C" void kernel_launch(void* const* d_in, const int* in_sizes, int n_in,
                              void* d_out, int out_size, void* d_ws, size_t ws_size,
                              hipStream_t stream) {
  const float* V  = (const float*)d_in[0];
  const float* K  = (const float*)d_in[1];
  const float* Q  = (const float*)d_in[2];
  const float* Wv = (const float*)d_in[3];
  const float* Wk = (const float*)d_in[4];
  const float* Wq = (const float*)d_in[5];
  const float* Wo = (const float*)d_in[6];
  const float* bo = (const float*)d_in[7];
  float* out = (float*)d_out;

  char* ws = (char*)d_ws;
  float* Mq  = (float*)(ws);                          // 16 KB
  f16* Wbig  = (f16*)(ws + (1ull << 20));             // 2 MB
  f16* q16   = (f16*)(ws + (3ull << 20));             // 16 MB
  f16* k16   = (f16*)(ws + (19ull << 20));            // 16 MB
  f16* v16   = (f16*)(ws + (35ull << 20));            // 16 MB
  f16* att   = (f16*)(ws + (51ull << 20));            // 16 MB -> total 67 MB

  wprep<<<1040, 256, 0, stream>>>(Wv, Wo, Wq, Wk, Wbig, Mq);
  prep2<<<4608, 256, 0, stream>>>(Q, K, V, Mq, q16, k16, v16);
  flash<<<dim3(64, 4), 256, 0, stream>>>(q16, k16, v16, att, 0);
  flash<<<dim3(64, 4), 256, 0, stream>>>(q16, k16, v16, att, 4);
  ogemm<<<dim3(64, 8), 256, 0, stream>>>(att, Wbig, bo, out);
}

// Round 7
// 263.001 us; speedup vs baseline: 1.0751x; 1.0751x over previous
//
#include <hip/hip_runtime.h>
#include <stdint.h>

typedef _Float16 f16;
typedef f16 half2_t __attribute__((ext_vector_type(2)));
typedef f16 half4_t __attribute__((ext_vector_type(4)));
typedef f16 half8_t __attribute__((ext_vector_type(8)));
typedef __fp16 fp16x2_t __attribute__((ext_vector_type(2)));
typedef float f32x4 __attribute__((ext_vector_type(4)));

#define N_ 4
#define S_ 2048
#define D_ 1024
#define H_ 16
#define HD_ 64
#define LOG2E 1.44269504088896340736f
#define SCALE_ 0.03125f   /* 1/sqrt(1024) */

typedef __attribute__((address_space(1))) void gvoid;
typedef __attribute__((address_space(3))) void lvoid;

__device__ __forceinline__ void load_lds16(const void* g, void* l) {
  __builtin_amdgcn_global_load_lds((gvoid*)(uintptr_t)g, (lvoid*)l, 16, 0, 0);
}

__device__ __forceinline__ f32x4 mfma32(half8_t a, half8_t b, f32x4 c) {
  return __builtin_amdgcn_mfma_f32_16x16x32_f16(a, b, c, 0, 0, 0);
}

__device__ __forceinline__ half2_t pack_f16(float a, float b) {
  fp16x2_t t = __builtin_amdgcn_cvt_pkrtz(a, b);
  return __builtin_bit_cast(half2_t, t);
}

// ---------------- wprep: Wbig (b<1024), Mq (1024..1039), V transpose (1040..5135) --
__global__ void wprep(const float* __restrict__ Wv, const float* __restrict__ Wo,
                      const float* __restrict__ Wq, const float* __restrict__ Wk,
                      const float* __restrict__ V,
                      f16* __restrict__ Wbig, float* __restrict__ Mq,
                      f16* __restrict__ v16) {
  __shared__ char smem[16384];  // used only by the V-transpose branch
  int b = blockIdx.x;
  if (b < 1024) {
    int j = b;
#pragma unroll
    for (int c = 0; c < 4; ++c) {
      int i = c * 256 + threadIdx.x;
      int h = i >> 6, dd = i & 63;
      const float* wo = Wo + (size_t)j * 1024 + h * 64;
      float acc = 0.f;
#pragma unroll 8
      for (int e = 0; e < 64; ++e) acc += Wv[e * 64 + dd] * wo[e];
      Wbig[(size_t)j * 1024 + i] = (f16)acc;
    }
  } else if (b < 1040) {
    int tid = (b - 1024) * 256 + threadIdx.x;  // 4096 threads
    int d = tid >> 6, e = tid & 63;
    float acc = 0.f;
#pragma unroll 8
    for (int r = 0; r < 64; ++r) acc += Wq[r * 64 + d] * Wk[r * 64 + e];
    Mq[d * 64 + e] = acc * (SCALE_ * LOG2E);
  } else {
    f16* lv = (f16*)smem;
    int b2 = b - 1040;  // 4096 = 4 n * 16 h * 64 sb32
    int n = b2 >> 10, hh = (b2 >> 6) & 15, sb = b2 & 63;
    int t = threadIdx.x;
    {
      int r = t >> 3, ic = t & 7;
      const float* src = V + ((size_t)(n * S_ + sb * 32 + r)) * D_ + hh * HD_ + ic * 8;
      f32x4 a = *(const f32x4*)src;
      f32x4 b3 = *(const f32x4*)(src + 4);
      half8_t hv;
#pragma unroll
      for (int j = 0; j < 4; ++j) { hv[j] = (f16)a[j]; hv[4 + j] = (f16)b3[j]; }
      *(half8_t*)(lv + r * 64 + ic * 8) = hv;
    }
    __syncthreads();
    {
      int mt = t >> 6, L = t & 63;
      int quad = L >> 4, ld = L & 15;
      half8_t o;
#pragma unroll
      for (int j = 0; j < 4; ++j) {
        o[j]     = lv[(quad * 4 + j) * 64 + mt * 16 + ld];
        o[4 + j] = lv[(quad * 4 + j + 16) * 64 + mt * 16 + ld];
      }
      *(half8_t*)(v16 + (((size_t)(n * 16 + hh) * 64 + sb) * 4 + mt) * 512 + L * 8) = o;
    }
  }
}

// ---------------- prep_qk: coalesced Q-proj + K cast ------------------------------
// Replaces prep2's b<512 branch (was 55.6us @ 30% HBM, latency-bound: lanes read
// 4KB-strided rows -> 64 scattered lines per load instr; 512 blocks, 2/CU).
// New: 1024 blocks = (n, sblk, head-half of 8 heads). Q staged to LDS via
// global_load_lds with PRE-SWIZZLED global source (slot d4 ^ (row&7); linear LDS
// dest per m104/m173; read side applies the same XOR -> bank-floor reads). Mq
// staged linear. K cast fully read-coalesced (lane=contiguous 32B) with the
// fragment relayout done in-register: chunk cc=dp*4+qd, offset (qd*16+r)*8 --
// algebra matches the original writer exactly. 48KB LDS -> 3 blocks/CU.
__global__ __launch_bounds__(256, 3) void prep_qk(const float* __restrict__ Q,
                                                  const float* __restrict__ K,
                                                  const float* __restrict__ Mq,
                                                  f16* __restrict__ q16,
                                                  f16* __restrict__ k16) {
  __shared__ char smem[49152];  // 32KB Q (swizzled slots) + 16KB Mq (f32)
  int b = blockIdx.x;           // 1024 = (n*128 + sblk)*2 + hhalf
  int hhalf = b & 1;
  int sblk = (b >> 1) & 127;
  int n = b >> 8;
  int t = threadIdx.x;
  int L = t & 63, w = t >> 6;

  // ---- stage Q: 16 rows x 8 heads x 64 f32, swizzled source ----
  const char* Qblk = (const char*)(Q + ((size_t)(n * S_ + sblk * 16)) * D_) + hhalf * 2048;
#pragma unroll
  for (int i = 0; i < 8; ++i) {
    int g = (w * 8 + i) * 64 + L;            // granule 0..2047 (16B each)
    int row = g >> 7, hhg = (g >> 4) & 7, sl = g & 15;
    load_lds16(Qblk + (size_t)row * 4096 + hhg * 256 + ((sl ^ (row & 7)) << 4),
               smem + (w * 8 + i) * 1024);
  }
  // ---- stage Mq: 64x64 f32 linear ----
#pragma unroll
  for (int j = 0; j < 4; ++j)
    load_lds16((const char*)Mq + (size_t)(((w * 4 + j) * 64 + L) << 4),
               smem + 32768 + (w * 4 + j) * 1024);

  // ---- K cast + relayout (reads coalesced; overlaps the staging latency) ----
  const char* Kblk = (const char*)(K + ((size_t)(n * S_ + sblk * 16)) * D_) + hhalf * 2048;
#pragma unroll
  for (int i = 0; i < 4; ++i) {
    int e = i * 256 + t;                     // f32x8 chunk id, 1024 per block
    int r = e >> 6, c6 = e & 63;             // row 0..15, chunk-in-row 0..63
    const char* src = Kblk + (size_t)r * 4096 + c6 * 32;
    f32x4 a = *(const f32x4*)src;
    f32x4 b2 = *(const f32x4*)(src + 16);
    half8_t hv;
#pragma unroll
    for (int jj = 0; jj < 4; ++jj) { hv[jj] = (f16)a[jj]; hv[4 + jj] = (f16)b2[jj]; }
    int hk = hhalf * 8 + (c6 >> 3), cc = c6 & 7, dp = cc >> 2, qd = cc & 3;
    *(half8_t*)(k16 + ((((size_t)(n * 16 + hk) * 128 + sblk) * 2 + dp) * 512) +
                (qd * 16 + r) * 8) = hv;
  }
  __syncthreads();  // drains global_load_lds

  // ---- Q-proj: thread (lq, hh8, eh) -> row lq, head, output cols [eh*32, +32) ----
  int lq = t & 15, hh8 = (t >> 4) & 7, eh = t >> 7;
  int head = hhalf * 8 + hh8;
  const float* mql = (const float*)(smem + 32768);
  f32x4 acc4[8];
#pragma unroll
  for (int i = 0; i < 8; ++i) acc4[i] = (f32x4){0.f, 0.f, 0.f, 0.f};
  for (int d4 = 0; d4 < 16; ++d4) {
    f32x4 qv = *(const f32x4*)(smem + lq * 2048 + hh8 * 256 + ((d4 ^ (lq & 7)) << 4));
#pragma unroll
    for (int dj = 0; dj < 4; ++dj) {
      const f32x4* mrow = (const f32x4*)(mql + (d4 * 4 + dj) * 64 + eh * 32);
      float qs = qv[dj];
#pragma unroll
      for (int i = 0; i < 8; ++i) acc4[i] += mrow[i] * qs;
    }
  }
  size_t cbase = ((size_t)((n * 16 + head) * 128 + sblk)) * 2;
#pragma unroll
  for (int qd = 0; qd < 4; ++qd) {
    half8_t hv;
    f32x4 a0 = acc4[qd * 2], a1 = acc4[qd * 2 + 1];
#pragma unroll
    for (int jj = 0; jj < 4; ++jj) { hv[jj] = (f16)a0[jj]; hv[4 + jj] = (f16)a1[jj]; }
    *(half8_t*)(q16 + (cbase + eh) * 512 + (qd * 16 + lq) * 8) = hv;
  }
}

// ---------------- flash v5: intra-wave software pipeline (round-5 version) --------
__global__ __launch_bounds__(256, 2) void flash(const f16* __restrict__ q16,
                                                const f16* __restrict__ k16,
                                                const f16* __restrict__ v16,
                                                f16* __restrict__ att) {
  int nh = blockIdx.x;   // 64 (n,h)
  int qt = blockIdx.y;   // 8 q-tiles of 256
  int L = threadIdx.x & 63, w = threadIdx.x >> 6;
  int lq = L & 15, quad = L >> 4;

  // q'' B-fragments for 4 slices of 16 q-rows each
  const half8_t* qg = (const half8_t*)q16;
  half8_t qB[4][2];
#pragma unroll
  for (int j = 0; j < 4; ++j) {
    size_t qc = ((size_t)(nh * 128 + qt * 16 + w * 4 + j)) * 2;
    qB[j][0] = qg[qc * 64 + L];
    qB[j][1] = qg[(qc + 1) * 64 + L];
  }

  f32x4 accO[4][4];
#pragma unroll
  for (int j = 0; j < 4; ++j)
#pragma unroll
    for (int i = 0; i < 4; ++i) accO[j][i] = (f32x4){0.f, 0.f, 0.f, 0.f};
  f32x4 lvec[4];
#pragma unroll
  for (int j = 0; j < 4; ++j) lvec[j] = (f32x4){0.f, 0.f, 0.f, 0.f};

  const char* kg = (const char*)k16 + (size_t)nh * 262144 + L * 16;
  const char* vg = (const char*)v16 + (size_t)nh * 262144 + L * 16;

  half8_t kfA[4], vfA[4], pb[4];
  f32x4 aQK[2][4];

#define QK16(KF)                                              \
  {                                                           \
    __builtin_amdgcn_s_setprio(1);                            \
    _Pragma("unroll")                                         \
    for (int u = 0; u < 2; ++u) {                             \
      _Pragma("unroll")                                       \
      for (int j = 0; j < 4; ++j) {                           \
        f32x4 a = (f32x4){0.f, 0.f, 0.f, 0.f};                \
        a = mfma32(KF[u * 2], qB[j][0], a);                   \
        a = mfma32(KF[u * 2 + 1], qB[j][1], a);               \
        aQK[u][j] = a;                                        \
      }                                                       \
    }                                                         \
    __builtin_amdgcn_s_setprio(0);                            \
  }

#define PV16(VF)                                              \
  {                                                           \
    __builtin_amdgcn_s_setprio(1);                            \
    _Pragma("unroll")                                         \
    for (int mt2 = 0; mt2 < 4; ++mt2) {                       \
      _Pragma("unroll")                                       \
      for (int j = 0; j < 4; ++j)                             \
        accO[j][mt2] = mfma32(VF[mt2], pb[j], accO[j][mt2]);  \
    }                                                         \
    __builtin_amdgcn_s_setprio(0);                            \
  }

#define EXPPACK                                                             \
  {                                                                         \
    half4_t pc[2][4];                                                       \
    _Pragma("unroll")                                                       \
    for (int u = 0; u < 2; ++u) {                                           \
      _Pragma("unroll")                                                     \
      for (int j = 0; j < 4; ++j) {                                         \
        f32x4 p;                                                            \
        _Pragma("unroll")                                                   \
        for (int r = 0; r < 4; ++r) p[r] = __builtin_amdgcn_exp2f(aQK[u][j][r]); \
        lvec[j] += p;                                                       \
        pc[u][j] = __builtin_shufflevector(pack_f16(p[0], p[1]),            \
                                           pack_f16(p[2], p[3]), 0, 1, 2, 3); \
      }                                                                     \
    }                                                                       \
    _Pragma("unroll")                                                       \
    for (int j = 0; j < 4; ++j)                                             \
      pb[j] = __builtin_shufflevector(pc[0][j], pc[1][j], 0, 1, 2, 3, 4, 5, 6, 7); \
  }

  // prologue: load k(0), v(0); QK(0); load k(1); exp/pack -> pb(0)
#pragma unroll
  for (int c = 0; c < 4; ++c) {
    kfA[c] = *(const half8_t*)(kg + c * 1024);
    vfA[c] = *(const half8_t*)(vg + c * 1024);
  }
  QK16(kfA);
#pragma unroll
  for (int c = 0; c < 4; ++c) kfA[c] = *(const half8_t*)(kg + 4096 + c * 1024);
  EXPPACK;

  for (int gg = 1; gg < 64; ++gg) {
    QK16(kfA);  // k(gg), loaded last iteration
    PV16(vfA);  // v(gg-1), loaded last iteration
    // refill: k(gg+1) and v(gg) — issued after their readers, land under exp+next QK
    if (gg + 1 < 64) {
      const char* kb = kg + (size_t)(gg + 1) * 4096;
#pragma unroll
      for (int c = 0; c < 4; ++c) kfA[c] = *(const half8_t*)(kb + c * 1024);
    }
    {
      const char* vb = vg + (size_t)gg * 4096;
#pragma unroll
      for (int c = 0; c < 4; ++c) vfA[c] = *(const half8_t*)(vb + c * 1024);
    }
    EXPPACK;  // pb(gg) — VALU, overlaps the 32-mfma cluster's pipe occupancy
  }
  PV16(vfA);  // v(63)

#undef QK16
#undef PV16
#undef EXPPACK

  int n = nh >> 4, h = nh & 15;
#pragma unroll
  for (int j = 0; j < 4; ++j) {
    float l = lvec[j][0] + lvec[j][1] + lvec[j][2] + lvec[j][3];
    l += __shfl_xor(l, 16, 64);
    l += __shfl_xor(l, 32, 64);
    float inv_l = 1.0f / l;
    int s = qt * 256 + w * 64 + j * 16 + lq;
    f16* orow = att + ((size_t)(n * S_ + s)) * D_ + h * HD_;
#pragma unroll
    for (int mt2 = 0; mt2 < 4; ++mt2) {
      half4_t o;
#pragma unroll
      for (int r = 0; r < 4; ++r) o[r] = (f16)(accO[j][mt2][r] * inv_l);
      *(half4_t*)(orow + mt2 * 16 + quad * 4) = o;
    }
  }
}

// ---------------- output GEMM: XOR-swizzled LDS, double-buffer, 1 barrier/iter ----
__global__ __launch_bounds__(256, 3) void ogemm(const f16* __restrict__ A, const f16* __restrict__ Bm,
                                                const float* __restrict__ bias, float* __restrict__ C) {
  __shared__ char lds[32768];  // buf[2] x (A 8K + B 8K)
  int bm = blockIdx.x, bn = blockIdx.y;
  int L = threadIdx.x & 63, w = threadIdx.x >> 6;
  int wm = w >> 1, wn = w & 1;
  int lq = L & 15, quad = L >> 4;
  int lr = L >> 2, lc = L & 3;
  int src_c = lc ^ (lr & 3);  // stage global chunk src_c into LDS slot lc
  f32x4 acc[16];
#pragma unroll
  for (int i = 0; i < 16; ++i) acc[i] = (f32x4){0.f, 0.f, 0.f, 0.f};

  const f16* ga0 = A + ((size_t)(bm * 128 + (w * 2) * 16 + lr)) * 1024 + src_c * 8;
  const f16* gb0 = Bm + ((size_t)(bn * 128 + (w * 2) * 16 + lr)) * 1024 + src_c * 8;

  // prologue: stage kt 0 and 1
#pragma unroll
  for (int t = 0; t < 2; ++t)
#pragma unroll
    for (int c = 0; c < 2; ++c) {
      load_lds16(ga0 + t * 32 + (size_t)c * 16 * 1024, lds + t * 16384 + (w * 2 + c) * 1024);
      load_lds16(gb0 + t * 32 + (size_t)c * 16 * 1024, lds + t * 16384 + 8192 + (w * 2 + c) * 1024);
    }
  __syncthreads();

  for (int kt = 0; kt < 32; ++kt) {
    const char* base = lds + (kt & 1) * 16384;
    half8_t af[4], bf[4];
#pragma unroll
    for (int t = 0; t < 4; ++t) {
      int ch = quad ^ (lq & 3);
      af[t] = *(const half8_t*)(base + (wm * 64 + t * 16 + lq) * 64 + ch * 16);
      bf[t] = *(const half8_t*)(base + 8192 + (wn * 64 + t * 16 + lq) * 64 + ch * 16);
    }
#pragma unroll
    for (int mt = 0; mt < 4; ++mt)
#pragma unroll
      for (int nt = 0; nt < 4; ++nt)
        acc[mt * 4 + nt] =
            __builtin_amdgcn_mfma_f32_16x16x32_f16(af[mt], bf[nt], acc[mt * 4 + nt], 0, 0, 0);
    __syncthreads();  // frag reads done; drains kt+1 loads (overlapped w/ MFMA)
    if (kt + 2 < 32) {
      char* dst = lds + (kt & 1) * 16384;
#pragma unroll
      for (int c = 0; c < 2; ++c) {
        load_lds16(ga0 + (kt + 2) * 32 + (size_t)c * 16 * 1024, dst + (w * 2 + c) * 1024);
        load_lds16(gb0 + (kt + 2) * 32 + (size_t)c * 16 * 1024, dst + 8192 + (w * 2 + c) * 1024);
      }
    }
  }

#pragma unroll
  for (int nt = 0; nt < 4; ++nt) {
    int col = bn * 128 + wn * 64 + nt * 16 + lq;
    float bv = bias[col];
#pragma unroll
    for (int mt = 0; mt < 4; ++mt) {
#pragma unroll
      for (int r = 0; r < 4; ++r) {
        int row = bm * 128 + wm * 64 + mt * 16 + quad * 4 + r;
        C[(size_t)row * 1024 + col] = acc[mt * 4 + nt][r] + bv;
      }
    }
  }
}

extern "C" void kernel_launch(void* const* d_in, const int* in_sizes, int n_in,
                              void* d_out, int out_size, void* d_ws, size_t ws_size,
                              hipStream_t stream) {
  const float* V  = (const float*)d_in[0];
  const float* K  = (const float*)d_in[1];
  const float* Q  = (const float*)d_in[2];
  const float* Wv = (const float*)d_in[3];
  const float* Wk = (const float*)d_in[4];
  const float* Wq = (const float*)d_in[5];
  const float* Wo = (const float*)d_in[6];
  const float* bo = (const float*)d_in[7];
  float* out = (float*)d_out;

  char* ws = (char*)d_ws;
  float* Mq  = (float*)(ws);                          // 16 KB
  f16* Wbig  = (f16*)(ws + (1ull << 20));             // 2 MB
  f16* q16   = (f16*)(ws + (3ull << 20));             // 16 MB
  f16* k16   = (f16*)(ws + (19ull << 20));            // 16 MB
  f16* v16   = (f16*)(ws + (35ull << 20));            // 16 MB
  f16* att   = (f16*)(ws + (51ull << 20));            // 16 MB -> total 67 MB

  wprep<<<5136, 256, 0, stream>>>(Wv, Wo, Wq, Wk, V, Wbig, Mq, v16);
  prep_qk<<<1024, 256, 0, stream>>>(Q, K, Mq, q16, k16);
  flash<<<dim3(64, 8), 256, 0, stream>>>(q16, k16, v16, att);
  ogemm<<<dim3(64, 8), 256, 0, stream>>>(att, Wbig, bo, out);
}